// Round 7
// baseline (831.765 us; speedup 1.0000x reference)
//
#include <hip/hip_runtime.h>

typedef __bf16 bf16x8 __attribute__((ext_vector_type(8)));
typedef __bf16 bf16x4 __attribute__((ext_vector_type(4)));
typedef float floatx4 __attribute__((ext_vector_type(4)));

#define GK 2048
#define S_LEN 2048
#define NH 16
#define DH 128

__device__ __forceinline__ void gl2lds16(const __bf16* g, __bf16* l) {
    __builtin_amdgcn_global_load_lds(
        (const __attribute__((address_space(1))) void*)g,
        (__attribute__((address_space(3))) void*)l, 16, 0, 0);
}

// ---------------------------------------------------------------------------
// Merged fp32->bf16 conversion: x (2M float4) then wq|wk|wv (3x1M float4)
// into xb and the concatenated wqkv.
// ---------------------------------------------------------------------------
__global__ __launch_bounds__(256) void cvt_all(const float* __restrict__ x,
                                               const float* __restrict__ wq,
                                               const float* __restrict__ wk,
                                               const float* __restrict__ wv,
                                               __bf16* __restrict__ xb,
                                               __bf16* __restrict__ wqkv) {
    const int NX = 2097152;              // 4096*2048/4
    const int NW = 1048576;              // 2048*2048/4
    int i = blockIdx.x * 256 + threadIdx.x;
    const float* src;
    __bf16* dst;
    int j;
    if (i < NX) { src = x; dst = xb; j = i; }
    else {
        j = i - NX;
        const int w = j >> 20;           // 0..2
        j &= (NW - 1);
        src = (w == 0) ? wq : (w == 1) ? wk : wv;
        dst = wqkv + (size_t)w * (NW * 4);
    }
    const float4 v = ((const float4*)src)[j];
    bf16x4 h;
    h[0] = (__bf16)v.x; h[1] = (__bf16)v.y; h[2] = (__bf16)v.z; h[3] = (__bf16)v.w;
    ((bf16x4*)dst)[j] = h;
}

// ---------------------------------------------------------------------------
// Pure-bf16 K-loop: C[m][n] = sum_k A[m][k] * W[n][k], both staged via
// global_load_lds width-16. 128x128 tile, BK=32, 4 waves, 4x4 MFMA/wave.
// ---------------------------------------------------------------------------
__device__ __forceinline__ void gemm_body(const __bf16* __restrict__ A,
                                          const __bf16* __restrict__ W,
                                          int m0, int n0,
                                          __bf16 (*As)[32], __bf16 (*Bs)[32],
                                          floatx4 (*acc)[4]) {
    const int t = threadIdx.x, lane = t & 63, wave = t >> 6;
    const int fr = lane & 15, fq = lane >> 4;
    const int wr = (wave >> 1) * 64, wc = (wave & 1) * 64;

    const __bf16* Ap = A + (size_t)(m0 + wave * 32 + (lane >> 2)) * GK + (lane & 3) * 8;
    const __bf16* Wp = W + (size_t)(n0 + wave * 32 + (lane >> 2)) * GK + (lane & 3) * 8;
    __bf16* lA0 = &As[wave * 32][0];
    __bf16* lA1 = &As[wave * 32 + 16][0];
    __bf16* lB0 = &Bs[wave * 32][0];
    __bf16* lB1 = &Bs[wave * 32 + 16][0];

    for (int k0 = 0; k0 < GK; k0 += 32) {
        gl2lds16(Ap, lA0);
        gl2lds16(Ap + (size_t)16 * GK, lA1);
        gl2lds16(Wp, lB0);
        gl2lds16(Wp + (size_t)16 * GK, lB1);
        Ap += 32; Wp += 32;
        __syncthreads();   // drains vmcnt + orders LDS

        bf16x8 af[4], bfg[4];
        for (int i = 0; i < 4; i++) af[i]  = *(const bf16x8*)&As[wr + i * 16 + fr][fq * 8];
        for (int j = 0; j < 4; j++) bfg[j] = *(const bf16x8*)&Bs[wc + j * 16 + fr][fq * 8];
        for (int i = 0; i < 4; i++)
            for (int j = 0; j < 4; j++)
                acc[i][j] = __builtin_amdgcn_mfma_f32_16x16x32_bf16(af[i], bfg[j], acc[i][j], 0, 0, 0);
        __syncthreads();
    }
}

// Fused QKV projection: A (4096x2048 bf16) x Wqkv (6144x2048 bf16).
// n<2048 -> qb, n<4096 -> kb (row-major); n>=4096 -> vbT ([b][h*128+d][s]).
__global__ __launch_bounds__(256) void gemm_qkv(const __bf16* __restrict__ A,
                                                const __bf16* __restrict__ W,
                                                __bf16* __restrict__ qb,
                                                __bf16* __restrict__ kb,
                                                __bf16* __restrict__ vbT) {
    __shared__ __align__(16) __bf16 As[128][32];
    __shared__ __align__(16) __bf16 Bs[128][32];
    const int m0 = blockIdx.y * 128, n0 = blockIdx.x * 128;
    floatx4 acc[4][4] = {};
    gemm_body(A, W, m0, n0, As, Bs, acc);

    const int lane = threadIdx.x & 63, wave = threadIdx.x >> 6;
    const int fr = lane & 15, fq = lane >> 4;
    const int wr = (wave >> 1) * 64, wc = (wave & 1) * 64;
    const int which = n0 >> 11;          // 0=q 1=k 2=v (block-uniform)
    const int nc0 = n0 & 2047;

    for (int i = 0; i < 4; i++)
        for (int j = 0; j < 4; j++) {
            const int row = m0 + wr + i * 16 + fq * 4;
            const int col = nc0 + wc + j * 16 + fr;
            if (which == 2) {
                __bf16* Cp = vbT + (((size_t)(row & ~2047)) << 11) +
                             (size_t)col * 2048 + (row & 2047);
                bf16x4 hv;
                for (int r = 0; r < 4; r++) hv[r] = (__bf16)acc[i][j][r];
                *(bf16x4*)Cp = hv;
            } else {
                __bf16* dst = which ? kb : qb;
                for (int r = 0; r < 4; r++)
                    dst[(size_t)(row + r) * 2048 + col] = (__bf16)acc[i][j][r];
            }
        }
}

// Out-projection: A (4096x2048 bf16) x Wo (2048x2048 bf16) -> fp32 out
__global__ __launch_bounds__(256) void gemm_out(const __bf16* __restrict__ A,
                                                const __bf16* __restrict__ W,
                                                float* __restrict__ C) {
    __shared__ __align__(16) __bf16 As[128][32];
    __shared__ __align__(16) __bf16 Bs[128][32];
    const int m0 = blockIdx.y * 128, n0 = blockIdx.x * 128;
    floatx4 acc[4][4] = {};
    gemm_body(A, W, m0, n0, As, Bs, acc);

    const int lane = threadIdx.x & 63, wave = threadIdx.x >> 6;
    const int fr = lane & 15, fq = lane >> 4;
    const int wr = (wave >> 1) * 64, wc = (wave & 1) * 64;
    for (int i = 0; i < 4; i++)
        for (int j = 0; j < 4; j++) {
            const int row = m0 + wr + i * 16 + fq * 4;
            const int col = n0 + wc + j * 16 + fr;
            for (int r = 0; r < 4; r++)
                C[(size_t)(row + r) * 2048 + col] = acc[i][j][r];
        }
}

// ---------------------------------------------------------------------------
// Fused RMSNorm + RoPE (y=0: q, y=1: k) + wo fp32->bf16 convert (y=2).
// rmsrope: 16 lanes per (b,s,h) row, bf16x8 per lane; RoPE pair via shfl_xor(8).
// ---------------------------------------------------------------------------
__global__ __launch_bounds__(256) void rmsrope(__bf16* __restrict__ qb,
                                               __bf16* __restrict__ kb,
                                               const float* __restrict__ rope,
                                               const float* __restrict__ qw,
                                               const float* __restrict__ kw,
                                               const float* __restrict__ wo,
                                               __bf16* __restrict__ wob) {
    const int t = threadIdx.x;
    if (blockIdx.y == 2) {               // wo convert: 4096 blocks x 256 f4
        const int i = blockIdx.x * 256 + t;
        const float4 v = ((const float4*)wo)[i];
        bf16x4 h;
        h[0] = (__bf16)v.x; h[1] = (__bf16)v.y; h[2] = (__bf16)v.z; h[3] = (__bf16)v.w;
        ((bf16x4*)wob)[i] = h;
        return;
    }
    const int row = blockIdx.x * 16 + (t >> 4);            // (b*S + s)*H + h
    const int c = t & 15;
    __bf16* p = (blockIdx.y ? kb : qb) + (size_t)row * DH + c * 8;
    const float* w = (blockIdx.y ? kw : qw) + c * 8;
    const int s = (row >> 4) & (S_LEN - 1);

    const bf16x8 v = *(const bf16x8*)p;
    float n[8];
    float ss = 0.f;
    for (int i = 0; i < 8; i++) { n[i] = (float)v[i]; ss += n[i] * n[i]; }
    ss += __shfl_xor(ss, 1, 64);
    ss += __shfl_xor(ss, 2, 64);
    ss += __shfl_xor(ss, 4, 64);
    ss += __shfl_xor(ss, 8, 64);
    const float inv = rsqrtf(ss * (1.0f / 128.0f) + 1e-6f);
    const float4 w0 = *(const float4*)w, w1 = *(const float4*)(w + 4);
    n[0] *= inv * w0.x; n[1] *= inv * w0.y; n[2] *= inv * w0.z; n[3] *= inv * w0.w;
    n[4] *= inv * w1.x; n[5] *= inv * w1.y; n[6] *= inv * w1.z; n[7] *= inv * w1.w;

    float pn[8];
    for (int i = 0; i < 8; i++) pn[i] = __shfl_xor(n[i], 8, 64);

    const float4* f = (const float4*)(rope + (size_t)s * 256 + (c & 7) * 32);
    bf16x8 o;
    if (c < 8) {
        for (int i = 0; i < 8; i++) o[i] = (__bf16)(f[i].x * n[i] + f[i].y * pn[i]);
    } else {
        for (int i = 0; i < 8; i++) o[i] = (__bf16)(f[i].z * pn[i] + f[i].w * n[i]);
    }
    *(bf16x8*)p = o;
}

// ---------------------------------------------------------------------------
// Flash attention, KV-split=2, fixed-max softmax. grid = 1024:
// bits [2:0]+[9:8] -> bh (XCD swizzle), [6:3] -> q-tile(128), [7] -> kv-split.
// Block = 4 waves x 32 q-rows, KV tile 32. l accumulated in VALU from the
// same bf16-rounded P fed to PV (numerics identical to the ones-column).
// VGPR capped via launch_bounds(256,5) for >=5 waves/SIMD.
// ---------------------------------------------------------------------------
__global__ __launch_bounds__(256, 5) void flash(const __bf16* __restrict__ Q,
                                                const __bf16* __restrict__ K,
                                                const __bf16* __restrict__ Vt_g,
                                                __bf16* __restrict__ Opart,
                                                float* __restrict__ lpart) {
    __shared__ __align__(16) __bf16 Ks[32][136];    // [kv][d], pad 8 (2-way free)
    __shared__ __align__(16) __bf16 Vt[128][32];    // [d][kv], chunk-swizzled
    __shared__ __align__(16) __bf16 Ps[4][32][40];  // per-wave P [qr][kv]

    const int t = threadIdx.x, lane = t & 63, wave = t >> 6;
    const int fr = lane & 15, fq = lane >> 4;
    const int id = blockIdx.x;                       // 0..1023
    const int bh    = (id & 7) + 8 * (id >> 8);      // XCD swizzle
    const int qidx  = (id >> 3) & 15;
    const int split = (id >> 7) & 1;
    const int b = bh >> 4, h = bh & 15;
    const size_t baseQ = (size_t)b * S_LEN * 2048 + h * 128;
    const size_t baseV = (size_t)b * 2048 * 2048 + (size_t)h * 128 * 2048;
    const int q0 = qidx * 128 + wave * 32;
    const int kv_lo = split * (S_LEN / 2);
    const float sc2 = 0.08838834764831845f * 1.4426950408889634f;  // (1/sqrt(128))*log2e
    const float M2 = 12.0f * 1.4426950408889634f;

    // Q fragments (A layout): 2 row-subtiles x 4 k-chunks
    bf16x8 qf[2][4];
    for (int i2 = 0; i2 < 2; i2++) {
        const __bf16* qp = Q + baseQ + (size_t)(q0 + i2 * 16 + fr) * 2048 + fq * 8;
        for (int c = 0; c < 4; c++) qf[i2][c] = *(const bf16x8*)(qp + c * 32);
    }

    floatx4 oa[2][8] = {};   // [q-subtile][8 d-tiles]
    float lacc[2][4] = {};   // VALU l accumulator

    const __bf16* Kp = K + baseQ + (size_t)(kv_lo + (t >> 3)) * 2048 + (t & 7) * 16;
    const int lrow = lane >> 2;
    const int src_chunk = ((lane & 3) - (lrow >> 1)) & 3;   // Vt chunk swizzle
    const __bf16* Vp = Vt_g + baseV + (size_t)(wave * 32 + lrow) * 2048 + src_chunk * 8 + kv_lo;
    __bf16* lV0 = &Vt[wave * 32][0];
    __bf16* lV1 = &Vt[wave * 32 + 16][0];

    for (int kv0 = 0; kv0 < S_LEN / 2; kv0 += 32) {
        *(uint4*)&Ks[t >> 3][(t & 7) * 16]     = *(const uint4*)(Kp);
        *(uint4*)&Ks[t >> 3][(t & 7) * 16 + 8] = *(const uint4*)(Kp + 8);
        gl2lds16(Vp, lV0);
        gl2lds16(Vp + (size_t)16 * 2048, lV1);
        Kp += (size_t)32 * 2048;
        Vp += 32;
        __syncthreads();   // drains vmcnt (V DMA) + LDS writes

        // S = Q K^T: 2 q-subtiles x 2 kv-subtiles
        floatx4 sacc[2][2] = {};
        for (int c = 0; c < 4; c++) {
            const bf16x8 kf0 = *(const bf16x8*)&Ks[fr][c * 32 + fq * 8];
            const bf16x8 kf1 = *(const bf16x8*)&Ks[fr + 16][c * 32 + fq * 8];
            sacc[0][0] = __builtin_amdgcn_mfma_f32_16x16x32_bf16(qf[0][c], kf0, sacc[0][0], 0, 0, 0);
            sacc[0][1] = __builtin_amdgcn_mfma_f32_16x16x32_bf16(qf[0][c], kf1, sacc[0][1], 0, 0, 0);
            sacc[1][0] = __builtin_amdgcn_mfma_f32_16x16x32_bf16(qf[1][c], kf0, sacc[1][0], 0, 0, 0);
            sacc[1][1] = __builtin_amdgcn_mfma_f32_16x16x32_bf16(qf[1][c], kf1, sacc[1][1], 0, 0, 0);
        }

        // P = exp2(s*sc2 - M2) -> LDS; l += bf16-rounded P (matches PV numerics)
        for (int i2 = 0; i2 < 2; i2++)
            for (int r = 0; r < 4; r++) {
                const int row = i2 * 16 + fq * 4 + r;
                const __bf16 pb0 = (__bf16)exp2f(fmaf(sc2, sacc[i2][0][r], -M2));
                const __bf16 pb1 = (__bf16)exp2f(fmaf(sc2, sacc[i2][1][r], -M2));
                Ps[wave][row][fr]      = pb0;
                Ps[wave][row][fr + 16] = pb1;
                lacc[i2][r] += (float)pb0 + (float)pb1;
            }

        // O += P V; per-wave Ps: no barrier needed.
        const bf16x8 pf0 = *(const bf16x8*)&Ps[wave][fr][fq * 8];
        const bf16x8 pf1 = *(const bf16x8*)&Ps[wave][16 + fr][fq * 8];
        const int vchunk = ((fq + (fr >> 1)) & 3) * 8;
        for (int nb = 0; nb < 8; nb++) {
            const bf16x8 vf = *(const bf16x8*)&Vt[nb * 16 + fr][vchunk];
            oa[0][nb] = __builtin_amdgcn_mfma_f32_16x16x32_bf16(pf0, vf, oa[0][nb], 0, 0, 0);
            oa[1][nb] = __builtin_amdgcn_mfma_f32_16x16x32_bf16(pf1, vf, oa[1][nb], 0, 0, 0);
        }
        __syncthreads();   // all tile reads done before next staging
    }

    // l reduce over the 16 fr-lanes (stays within the fq group: xor bits 0..3)
    for (int i2 = 0; i2 < 2; i2++)
        for (int r = 0; r < 4; r++) {
            float l = lacc[i2][r];
            l += __shfl_xor(l, 1, 64);
            l += __shfl_xor(l, 2, 64);
            l += __shfl_xor(l, 4, 64);
            l += __shfl_xor(l, 8, 64);
            lacc[i2][r] = l;
        }

    // Unnormalized partials: Opart[split][bh][q][128] bf16, lpart[split][bh][q]
    const size_t bhq = ((size_t)split * 32 + bh) * 2048;
    for (int i2 = 0; i2 < 2; i2++)
        for (int r = 0; r < 4; r++) {
            const int q = q0 + i2 * 16 + fq * 4 + r;
            __bf16* op = Opart + (bhq + q) * 128;
            for (int nb = 0; nb < 8; nb++)
                op[nb * 16 + fr] = (__bf16)(oa[i2][nb][r]);
            if (fr == 0) lpart[bhq + q] = lacc[i2][r];
        }
}

// ---------------------------------------------------------------------------
// Combine the 2 KV-splits: O = (O0+O1)/(l0+l1); write ob[b][q][h*128+d].
// ---------------------------------------------------------------------------
__global__ __launch_bounds__(256) void flash_reduce(const __bf16* __restrict__ Opart,
                                                    const float* __restrict__ lpart,
                                                    __bf16* __restrict__ ob) {
    const int t = threadIdx.x;
    const int row = blockIdx.x * 16 + (t >> 4);   // bh*2048 + q, 0..65535
    const int c = (t & 15) * 8;
    const size_t SPL = (size_t)32 * 2048 * 128;
    const bf16x8 a = *(const bf16x8*)(Opart + (size_t)row * 128 + c);
    const bf16x8 d = *(const bf16x8*)(Opart + SPL + (size_t)row * 128 + c);
    const float inv = 1.0f / (lpart[row] + lpart[row + 65536]);
    bf16x8 o;
    for (int i = 0; i < 8; i++) o[i] = (__bf16)(((float)a[i] + (float)d[i]) * inv);
    const int bh = row >> 11, q = row & 2047;
    const int b = bh >> 4, h = bh & 15;
    *(bf16x8*)(ob + ((size_t)(b * 2048 + q) * 2048) + h * 128 + c) = o;
}

// ---------------------------------------------------------------------------
extern "C" void kernel_launch(void* const* d_in, const int* in_sizes, int n_in,
                              void* d_out, int out_size, void* d_ws, size_t ws_size,
                              hipStream_t stream) {
    const float* x    = (const float*)d_in[0];
    const float* rope = (const float*)d_in[1];
    const float* wq   = (const float*)d_in[2];
    const float* wk   = (const float*)d_in[3];
    const float* wv   = (const float*)d_in[4];
    const float* wo   = (const float*)d_in[5];
    const float* qnw  = (const float*)d_in[6];
    const float* knw  = (const float*)d_in[7];
    float* out = (float*)d_out;

    const size_t NTOK = 2 * 2048;
    const size_t ELEMS = NTOK * 2048;            // 8388608
    __bf16* xb  = (__bf16*)d_ws;                 // x-bf16 (16MB); after gemm_qkv: wob + lpart
    __bf16* qb  = xb + ELEMS;                    // q
    __bf16* kb  = qb + ELEMS;                    // k; after flash: attention-out (ob)
    __bf16* vbT = kb + ELEMS;                    // v^T
    // d_out (33.55 MB): wqkv bf16 (25.2 MB) -> consumed by gemm_qkv; then
    // flash O-partials (33.55 MB) -> consumed by flash_reduce; then final out.
    __bf16* wqkv  = (__bf16*)d_out;
    __bf16* Opart = (__bf16*)d_out;
    __bf16* wob   = xb;                          // wo bf16 (8.39 MB), after gemm_qkv
    float*  lpart = (float*)((char*)d_ws + 8388608 + 4194304);  // 512 KB, in xb region
    __bf16* ob    = kb;

    cvt_all<<<dim3(20480), 256, 0, stream>>>(x, wq, wk, wv, xb, wqkv);
    gemm_qkv<<<dim3(6144 / 128, (unsigned)(NTOK / 128)), 256, 0, stream>>>(xb, wqkv, qb, kb, vbT);
    rmsrope<<<dim3(4096, 3), 256, 0, stream>>>(qb, kb, rope, qnw, knw, wo, wob);
    flash<<<dim3(1024), 256, 0, stream>>>(qb, kb, vbT, Opart, lpart);
    flash_reduce<<<dim3(65536 / 16), 256, 0, stream>>>(Opart, lpart, ob);
    gemm_out<<<dim3(2048 / 128, (unsigned)(NTOK / 128)), 256, 0, stream>>>(ob, wob, out);
}

// Round 8
// 477.142 us; speedup vs baseline: 1.7432x; 1.7432x over previous
//
#include <hip/hip_runtime.h>

typedef __bf16 bf16x8 __attribute__((ext_vector_type(8)));
typedef __bf16 bf16x4 __attribute__((ext_vector_type(4)));
typedef float floatx4 __attribute__((ext_vector_type(4)));

#define GK 2048
#define S_LEN 2048
#define NH 16
#define DH 128

__device__ __forceinline__ void gl2lds16(const __bf16* g, __bf16* l) {
    __builtin_amdgcn_global_load_lds(
        (const __attribute__((address_space(1))) void*)g,
        (__attribute__((address_space(3))) void*)l, 16, 0, 0);
}

// ---------------------------------------------------------------------------
// Merged fp32->bf16 conversion: x (2M float4) then wq|wk|wv (3x1M float4).
// ---------------------------------------------------------------------------
__global__ __launch_bounds__(256) void cvt_all(const float* __restrict__ x,
                                               const float* __restrict__ wq,
                                               const float* __restrict__ wk,
                                               const float* __restrict__ wv,
                                               __bf16* __restrict__ xb,
                                               __bf16* __restrict__ wqkv) {
    const int NX = 2097152;              // 4096*2048/4
    const int NW = 1048576;              // 2048*2048/4
    int i = blockIdx.x * 256 + threadIdx.x;
    const float* src;
    __bf16* dst;
    int j;
    if (i < NX) { src = x; dst = xb; j = i; }
    else {
        j = i - NX;
        const int w = j >> 20;           // 0..2
        j &= (NW - 1);
        src = (w == 0) ? wq : (w == 1) ? wk : wv;
        dst = wqkv + (size_t)w * (NW * 4);
    }
    const float4 v = ((const float4*)src)[j];
    bf16x4 h;
    h[0] = (__bf16)v.x; h[1] = (__bf16)v.y; h[2] = (__bf16)v.z; h[3] = (__bf16)v.w;
    ((bf16x4*)dst)[j] = h;
}

// ---------------------------------------------------------------------------
// Pure-bf16 K-loop: C[m][n] = sum_k A[m][k] * W[n][k], both staged via
// global_load_lds width-16. 128x128 tile, BK=32, 4 waves, 4x4 MFMA/wave.
// ---------------------------------------------------------------------------
__device__ __forceinline__ void gemm_body(const __bf16* __restrict__ A,
                                          const __bf16* __restrict__ W,
                                          int m0, int n0,
                                          __bf16 (*As)[32], __bf16 (*Bs)[32],
                                          floatx4 (*acc)[4]) {
    const int t = threadIdx.x, lane = t & 63, wave = t >> 6;
    const int fr = lane & 15, fq = lane >> 4;
    const int wr = (wave >> 1) * 64, wc = (wave & 1) * 64;

    const __bf16* Ap = A + (size_t)(m0 + wave * 32 + (lane >> 2)) * GK + (lane & 3) * 8;
    const __bf16* Wp = W + (size_t)(n0 + wave * 32 + (lane >> 2)) * GK + (lane & 3) * 8;
    __bf16* lA0 = &As[wave * 32][0];
    __bf16* lA1 = &As[wave * 32 + 16][0];
    __bf16* lB0 = &Bs[wave * 32][0];
    __bf16* lB1 = &Bs[wave * 32 + 16][0];

    for (int k0 = 0; k0 < GK; k0 += 32) {
        gl2lds16(Ap, lA0);
        gl2lds16(Ap + (size_t)16 * GK, lA1);
        gl2lds16(Wp, lB0);
        gl2lds16(Wp + (size_t)16 * GK, lB1);
        Ap += 32; Wp += 32;
        __syncthreads();   // drains vmcnt + orders LDS

        bf16x8 af[4], bfg[4];
        for (int i = 0; i < 4; i++) af[i]  = *(const bf16x8*)&As[wr + i * 16 + fr][fq * 8];
        for (int j = 0; j < 4; j++) bfg[j] = *(const bf16x8*)&Bs[wc + j * 16 + fr][fq * 8];
        for (int i = 0; i < 4; i++)
            for (int j = 0; j < 4; j++)
                acc[i][j] = __builtin_amdgcn_mfma_f32_16x16x32_bf16(af[i], bfg[j], acc[i][j], 0, 0, 0);
        __syncthreads();
    }
}

// Fused QKV projection: A (4096x2048 bf16) x Wqkv (6144x2048 bf16).
// n<2048 -> qb, n<4096 -> kb (row-major); n>=4096 -> vbT ([b][h*128+d][s]).
__global__ __launch_bounds__(256) void gemm_qkv(const __bf16* __restrict__ A,
                                                const __bf16* __restrict__ W,
                                                __bf16* __restrict__ qb,
                                                __bf16* __restrict__ kb,
                                                __bf16* __restrict__ vbT) {
    __shared__ __align__(16) __bf16 As[128][32];
    __shared__ __align__(16) __bf16 Bs[128][32];
    const int m0 = blockIdx.y * 128, n0 = blockIdx.x * 128;
    floatx4 acc[4][4] = {};
    gemm_body(A, W, m0, n0, As, Bs, acc);

    const int lane = threadIdx.x & 63, wave = threadIdx.x >> 6;
    const int fr = lane & 15, fq = lane >> 4;
    const int wr = (wave >> 1) * 64, wc = (wave & 1) * 64;
    const int which = n0 >> 11;          // 0=q 1=k 2=v (block-uniform)
    const int nc0 = n0 & 2047;

    for (int i = 0; i < 4; i++)
        for (int j = 0; j < 4; j++) {
            const int row = m0 + wr + i * 16 + fq * 4;
            const int col = nc0 + wc + j * 16 + fr;
            if (which == 2) {
                __bf16* Cp = vbT + (((size_t)(row & ~2047)) << 11) +
                             (size_t)col * 2048 + (row & 2047);
                bf16x4 hv;
                for (int r = 0; r < 4; r++) hv[r] = (__bf16)acc[i][j][r];
                *(bf16x4*)Cp = hv;
            } else {
                __bf16* dst = which ? kb : qb;
                for (int r = 0; r < 4; r++)
                    dst[(size_t)(row + r) * 2048 + col] = (__bf16)acc[i][j][r];
            }
        }
}

// Out-projection: A (4096x2048 bf16) x Wo (2048x2048 bf16) -> fp32 out
__global__ __launch_bounds__(256) void gemm_out(const __bf16* __restrict__ A,
                                                const __bf16* __restrict__ W,
                                                float* __restrict__ C) {
    __shared__ __align__(16) __bf16 As[128][32];
    __shared__ __align__(16) __bf16 Bs[128][32];
    const int m0 = blockIdx.y * 128, n0 = blockIdx.x * 128;
    floatx4 acc[4][4] = {};
    gemm_body(A, W, m0, n0, As, Bs, acc);

    const int lane = threadIdx.x & 63, wave = threadIdx.x >> 6;
    const int fr = lane & 15, fq = lane >> 4;
    const int wr = (wave >> 1) * 64, wc = (wave & 1) * 64;
    for (int i = 0; i < 4; i++)
        for (int j = 0; j < 4; j++) {
            const int row = m0 + wr + i * 16 + fq * 4;
            const int col = n0 + wc + j * 16 + fr;
            for (int r = 0; r < 4; r++)
                C[(size_t)(row + r) * 2048 + col] = acc[i][j][r];
        }
}

// ---------------------------------------------------------------------------
// Fused RMSNorm + RoPE (y=0: q, y=1: k) + wo fp32->bf16 convert (y=2).
// ---------------------------------------------------------------------------
__global__ __launch_bounds__(256) void rmsrope(__bf16* __restrict__ qb,
                                               __bf16* __restrict__ kb,
                                               const float* __restrict__ rope,
                                               const float* __restrict__ qw,
                                               const float* __restrict__ kw,
                                               const float* __restrict__ wo,
                                               __bf16* __restrict__ wob) {
    const int t = threadIdx.x;
    if (blockIdx.y == 2) {               // wo convert: 4096 blocks x 256 f4
        const int i = blockIdx.x * 256 + t;
        const float4 v = ((const float4*)wo)[i];
        bf16x4 h;
        h[0] = (__bf16)v.x; h[1] = (__bf16)v.y; h[2] = (__bf16)v.z; h[3] = (__bf16)v.w;
        ((bf16x4*)wob)[i] = h;
        return;
    }
    const int row = blockIdx.x * 16 + (t >> 4);            // (b*S + s)*H + h
    const int c = t & 15;
    __bf16* p = (blockIdx.y ? kb : qb) + (size_t)row * DH + c * 8;
    const float* w = (blockIdx.y ? kw : qw) + c * 8;
    const int s = (row >> 4) & (S_LEN - 1);

    const bf16x8 v = *(const bf16x8*)p;
    float n[8];
    float ss = 0.f;
    for (int i = 0; i < 8; i++) { n[i] = (float)v[i]; ss += n[i] * n[i]; }
    ss += __shfl_xor(ss, 1, 64);
    ss += __shfl_xor(ss, 2, 64);
    ss += __shfl_xor(ss, 4, 64);
    ss += __shfl_xor(ss, 8, 64);
    const float inv = rsqrtf(ss * (1.0f / 128.0f) + 1e-6f);
    const float4 w0 = *(const float4*)w, w1 = *(const float4*)(w + 4);
    n[0] *= inv * w0.x; n[1] *= inv * w0.y; n[2] *= inv * w0.z; n[3] *= inv * w0.w;
    n[4] *= inv * w1.x; n[5] *= inv * w1.y; n[6] *= inv * w1.z; n[7] *= inv * w1.w;

    float pn[8];
    for (int i = 0; i < 8; i++) pn[i] = __shfl_xor(n[i], 8, 64);

    const float4* f = (const float4*)(rope + (size_t)s * 256 + (c & 7) * 32);
    bf16x8 o;
    if (c < 8) {
        for (int i = 0; i < 8; i++) o[i] = (__bf16)(f[i].x * n[i] + f[i].y * pn[i]);
    } else {
        for (int i = 0; i < 8; i++) o[i] = (__bf16)(f[i].z * pn[i] + f[i].w * n[i]);
    }
    *(bf16x8*)p = o;
}

// ---------------------------------------------------------------------------
// Flash attention, no split, fixed-max softmax (p = exp2(s*sc2 - M2)).
// grid = 512: bits [2:0]+[8:7] -> bh (XCD swizzle: each XCD sees 4 heads),
// [6:3] -> q-tile(128). Block = 4 waves x 32 q-rows, KV tile 32, 64 iters.
// l accumulated in VALU from the same bf16-rounded P fed to PV. Vt staged via
// global_load_lds with chunk swizzle (2-way-bank-free reads). Output written
// normalized, IN-PLACE over the Q buffer ([b][q][h*128+d]): each block's
// output range equals its own (preloaded) Q range, so no cross-block hazard.
// ---------------------------------------------------------------------------
__global__ __launch_bounds__(256) void flash(const __bf16* __restrict__ Q,
                                             const __bf16* __restrict__ K,
                                             const __bf16* __restrict__ Vt_g,
                                             __bf16* __restrict__ O) {
    __shared__ __align__(16) __bf16 Ks[32][136];    // [kv][d], pad 8 (2-way free)
    __shared__ __align__(16) __bf16 Vt[128][32];    // [d][kv], chunk-swizzled
    __shared__ __align__(16) __bf16 Ps[4][32][40];  // per-wave P [qr][kv]

    const int t = threadIdx.x, lane = t & 63, wave = t >> 6;
    const int fr = lane & 15, fq = lane >> 4;
    const int id = blockIdx.x;                       // 0..511
    const int bh   = (id & 7) + 8 * (id >> 7);       // XCD swizzle
    const int qidx = (id >> 3) & 15;
    const int b = bh >> 4, h = bh & 15;
    const size_t baseQ = (size_t)b * S_LEN * 2048 + h * 128;
    const size_t baseV = (size_t)b * 2048 * 2048 + (size_t)h * 128 * 2048;
    const int q0 = qidx * 128 + wave * 32;
    const float sc2 = 0.08838834764831845f * 1.4426950408889634f;  // (1/sqrt(128))*log2e
    const float M2 = 12.0f * 1.4426950408889634f;

    // Q fragments (A layout): 2 row-subtiles x 4 k-chunks (read before any O write)
    bf16x8 qf[2][4];
    for (int i2 = 0; i2 < 2; i2++) {
        const __bf16* qp = Q + baseQ + (size_t)(q0 + i2 * 16 + fr) * 2048 + fq * 8;
        for (int c = 0; c < 4; c++) qf[i2][c] = *(const bf16x8*)(qp + c * 32);
    }

    floatx4 oa[2][8] = {};   // [q-subtile][8 d-tiles]
    float lacc[2][4] = {};   // VALU l accumulator

    const __bf16* Kp = K + baseQ + (size_t)(t >> 3) * 2048 + (t & 7) * 16;
    const int lrow = lane >> 2;
    const int src_chunk = ((lane & 3) - (lrow >> 1)) & 3;   // Vt chunk swizzle
    const __bf16* Vp = Vt_g + baseV + (size_t)(wave * 32 + lrow) * 2048 + src_chunk * 8;
    __bf16* lV0 = &Vt[wave * 32][0];
    __bf16* lV1 = &Vt[wave * 32 + 16][0];

    for (int kv0 = 0; kv0 < S_LEN; kv0 += 32) {
        *(uint4*)&Ks[t >> 3][(t & 7) * 16]     = *(const uint4*)(Kp);
        *(uint4*)&Ks[t >> 3][(t & 7) * 16 + 8] = *(const uint4*)(Kp + 8);
        gl2lds16(Vp, lV0);
        gl2lds16(Vp + (size_t)16 * 2048, lV1);
        Kp += (size_t)32 * 2048;
        Vp += 32;
        __syncthreads();   // drains vmcnt (V DMA) + LDS writes

        // S = Q K^T: 2 q-subtiles x 2 kv-subtiles
        floatx4 sacc[2][2] = {};
        for (int c = 0; c < 4; c++) {
            const bf16x8 kf0 = *(const bf16x8*)&Ks[fr][c * 32 + fq * 8];
            const bf16x8 kf1 = *(const bf16x8*)&Ks[fr + 16][c * 32 + fq * 8];
            sacc[0][0] = __builtin_amdgcn_mfma_f32_16x16x32_bf16(qf[0][c], kf0, sacc[0][0], 0, 0, 0);
            sacc[0][1] = __builtin_amdgcn_mfma_f32_16x16x32_bf16(qf[0][c], kf1, sacc[0][1], 0, 0, 0);
            sacc[1][0] = __builtin_amdgcn_mfma_f32_16x16x32_bf16(qf[1][c], kf0, sacc[1][0], 0, 0, 0);
            sacc[1][1] = __builtin_amdgcn_mfma_f32_16x16x32_bf16(qf[1][c], kf1, sacc[1][1], 0, 0, 0);
        }

        // P = exp2(s*sc2 - M2) -> LDS; l += bf16-rounded P (matches PV numerics)
        for (int i2 = 0; i2 < 2; i2++)
            for (int r = 0; r < 4; r++) {
                const int row = i2 * 16 + fq * 4 + r;
                const __bf16 pb0 = (__bf16)exp2f(fmaf(sc2, sacc[i2][0][r], -M2));
                const __bf16 pb1 = (__bf16)exp2f(fmaf(sc2, sacc[i2][1][r], -M2));
                Ps[wave][row][fr]      = pb0;
                Ps[wave][row][fr + 16] = pb1;
                lacc[i2][r] += (float)pb0 + (float)pb1;
            }

        // O += P V; per-wave Ps: no barrier needed.
        const bf16x8 pf0 = *(const bf16x8*)&Ps[wave][fr][fq * 8];
        const bf16x8 pf1 = *(const bf16x8*)&Ps[wave][16 + fr][fq * 8];
        const int vchunk = ((fq + (fr >> 1)) & 3) * 8;
        for (int nb = 0; nb < 8; nb++) {
            const bf16x8 vf = *(const bf16x8*)&Vt[nb * 16 + fr][vchunk];
            oa[0][nb] = __builtin_amdgcn_mfma_f32_16x16x32_bf16(pf0, vf, oa[0][nb], 0, 0, 0);
            oa[1][nb] = __builtin_amdgcn_mfma_f32_16x16x32_bf16(pf1, vf, oa[1][nb], 0, 0, 0);
        }
        __syncthreads();   // all tile reads done before next staging
    }

    // l reduce over the 16 fr-lanes (xor bits 0..3 stay within the fq group)
    for (int i2 = 0; i2 < 2; i2++)
        for (int r = 0; r < 4; r++) {
            float l = lacc[i2][r];
            l += __shfl_xor(l, 1, 64);
            l += __shfl_xor(l, 2, 64);
            l += __shfl_xor(l, 4, 64);
            l += __shfl_xor(l, 8, 64);
            lacc[i2][r] = l;
        }

    // Normalized output, in-place over Q
    for (int i2 = 0; i2 < 2; i2++)
        for (int r = 0; r < 4; r++) {
            const int q = q0 + i2 * 16 + fq * 4 + r;
            const float inv = 1.0f / lacc[i2][r];
            __bf16* op = O + baseQ + (size_t)q * 2048;
            for (int nb = 0; nb < 8; nb++)
                op[nb * 16 + fr] = (__bf16)(oa[i2][nb][r] * inv);
        }
}

// ---------------------------------------------------------------------------
extern "C" void kernel_launch(void* const* d_in, const int* in_sizes, int n_in,
                              void* d_out, int out_size, void* d_ws, size_t ws_size,
                              hipStream_t stream) {
    const float* x    = (const float*)d_in[0];
    const float* rope = (const float*)d_in[1];
    const float* wq   = (const float*)d_in[2];
    const float* wk   = (const float*)d_in[3];
    const float* wv   = (const float*)d_in[4];
    const float* wo   = (const float*)d_in[5];
    const float* qnw  = (const float*)d_in[6];
    const float* knw  = (const float*)d_in[7];
    float* out = (float*)d_out;

    const size_t NTOK = 2 * 2048;
    const size_t ELEMS = NTOK * 2048;            // 8388608
    __bf16* xb  = (__bf16*)d_ws;                 // x-bf16; after gemm_qkv: wob
    __bf16* qb  = xb + ELEMS;                    // q; flash overwrites in-place with ob
    __bf16* kb  = qb + ELEMS;                    // k
    __bf16* vbT = kb + ELEMS;                    // v^T
    // d_out (33.55 MB): wqkv bf16 (25.2 MB) -> consumed by gemm_qkv; then final out.
    __bf16* wqkv = (__bf16*)d_out;
    __bf16* wob  = xb;                           // wo bf16 (8.39 MB), written by rmsrope y=2
    __bf16* ob   = qb;                           // flash output, in-place

    cvt_all<<<dim3(20480), 256, 0, stream>>>(x, wq, wk, wv, xb, wqkv);
    gemm_qkv<<<dim3(6144 / 128, (unsigned)(NTOK / 128)), 256, 0, stream>>>(xb, wqkv, qb, kb, vbT);
    rmsrope<<<dim3(4096, 3), 256, 0, stream>>>(qb, kb, rope, qnw, knw, wo, wob);
    flash<<<dim3(512), 256, 0, stream>>>(qb, kb, vbT, ob);
    gemm_out<<<dim3(2048 / 128, (unsigned)(NTOK / 128)), 256, 0, stream>>>(ob, wob, out);
}